// Round 10
// baseline (239.068 us; speedup 1.0000x reference)
//
#include <hip/hip_runtime.h>

#define BATCH   131072
#define NHID    128
#define BM      32      // batch rows per tile
#define TPB     512     // 8 waves
#define NBLK    256     // persistent blocks (1 per CU)
#define NTILE   (BATCH / BM)     // 4096
#define TPBLK   (NTILE / NBLK)   // 16 tiles per block

typedef __bf16 bf16_t;
typedef __bf16 bf16x8 __attribute__((ext_vector_type(8)));
typedef float  f32x4  __attribute__((ext_vector_type(4)));

__device__ __forceinline__ float fsigmoid(float v) {
    return __builtin_amdgcn_rcpf(1.0f + __builtin_amdgcn_exp2f(v * -1.44269504f));
}
__device__ __forceinline__ float ftanh(float v) {
    return __builtin_fmaf(-2.0f,
        __builtin_amdgcn_rcpf(1.0f + __builtin_amdgcn_exp2f(v * 2.88539008f)), 1.0f);
}
__device__ __forceinline__ f32x4 vsig(f32x4 v) {
    f32x4 r;
    #pragma unroll
    for (int i = 0; i < 4; ++i) r[i] = fsigmoid(v[i]);
    return r;
}
__device__ __forceinline__ f32x4 vtanh(f32x4 v) {
    f32x4 r;
    #pragma unroll
    for (int i = 0; i < 4; ++i) r[i] = ftanh(v[i]);
    return r;
}

// Pack W4p[p][k] (bf16) with p = w*64 + t*16 + c  ->  gate t, output col j = w*16 + c.
__global__ void prep_kernel(const float* __restrict__ Wf, const float* __restrict__ Wi,
                            const float* __restrict__ Wc, const float* __restrict__ Wo,
                            const float* __restrict__ bfp, const float* __restrict__ bip,
                            const float* __restrict__ bcp, const float* __restrict__ bop,
                            const float* __restrict__ Wfc,
                            bf16_t* __restrict__ W4p, float* __restrict__ b4p,
                            bf16_t* __restrict__ Wfcb)
{
    int id = blockIdx.x * 256 + threadIdx.x;
    if (id < 512 * 256) {
        int p = id >> 8, k = id & 255;
        int w = p >> 6, t = (p >> 4) & 3, c = p & 15;
        int j = w * 16 + c;
        const float* W = (t == 0) ? Wf : (t == 1) ? Wi : (t == 2) ? Wc : Wo;
        W4p[id] = (bf16_t)W[j * 256 + k];
        if (k == 0) {
            const float* bs = (t == 0) ? bfp : (t == 1) ? bip : (t == 2) ? bcp : bop;
            b4p[p] = bs[j];
        }
    } else {
        int id2 = id - 512 * 256;
        if (id2 < 128 * 128) Wfcb[id2] = (bf16_t)Wfc[id2];
    }
}

// K1: gates GEMM + LSTM elementwise. NO LDS, NO barriers -- waves self-pace,
// so the memory pipeline never drains globally. A-fragments read from L2
// (8 waves/block share the tile); free VGPRs let the compiler pipeline them.
__global__ __launch_bounds__(TPB, 2) void lstm_gates(
    const float* __restrict__ x, const float* __restrict__ hidden, const float* __restrict__ ctx,
    const bf16_t* __restrict__ W4p, const float* __restrict__ b4p,
    float* __restrict__ hid_out, float* __restrict__ ctx_out)
{
    const int tid  = threadIdx.x;
    const int lane = tid & 63;
    const int wv   = tid >> 6;     // 0..7
    const int l16  = lane & 15;
    const int lq   = lane >> 4;    // 0..3
    const int tile0 = blockIdx.x * TPBLK;
    const int colb  = wv * 16 + lq * 4;     // lane's 4 consecutive output cols

    // ---- resident weights: B1 = this wave's 64 packed gate-rows (128 VGPR) ----
    bf16x8 B1[32];   // [pm*8 + ks]
    {
        const bf16_t* Bp = W4p + (wv * 64 + l16) * 256 + lq * 8;
        #pragma unroll
        for (int pm = 0; pm < 4; ++pm)
            #pragma unroll
            for (int ks = 0; ks < 8; ++ks)
                B1[pm * 8 + ks] = *(const bf16x8*)(Bp + pm * 16 * 256 + ks * 32);
    }
    const f32x4 bf4 = *(const f32x4*)(b4p + wv * 64 +  0 + lq * 4);
    const f32x4 bi4 = *(const f32x4*)(b4p + wv * 64 + 16 + lq * 4);
    const f32x4 bc4 = *(const f32x4*)(b4p + wv * 64 + 32 + lq * 4);
    const f32x4 bo4 = *(const f32x4*)(b4p + wv * 64 + 48 + lq * 4);

    f32x4 ctxA[2], ctxB[2];
    {   // prologue: ctx for tile 0
        const float* cp = ctx + (size_t)(tile0 * BM) * NHID + colb;
        ctxA[0] = *(const f32x4*)(cp + (size_t)l16 * NHID);
        ctxA[1] = *(const f32x4*)(cp + (size_t)(16 + l16) * NHID);
    }

    for (int t = 0; t < TPBLK; ++t) {
        const int row0 = (tile0 + t) * BM;

        // prefetch next tile's ctx (arrives during this tile's GEMM)
        {
            const int tn = (t + 1 < TPBLK) ? t + 1 : TPBLK - 1;
            const float* cp = ctx + (size_t)((tile0 + tn) * BM) * NHID + colb;
            ctxB[0] = *(const f32x4*)(cp + (size_t)l16 * NHID);
            ctxB[1] = *(const f32x4*)(cp + (size_t)(16 + l16) * NHID);
        }

        // GEMM1 (transposed): gates^T = W4 . cat^T ; A-fragments from global/L2
        f32x4 acc[4][2];
        #pragma unroll
        for (int pm = 0; pm < 4; ++pm) {
            acc[pm][0] = f32x4{0.f, 0.f, 0.f, 0.f};
            acc[pm][1] = f32x4{0.f, 0.f, 0.f, 0.f};
        }
        #pragma unroll
        for (int ks = 0; ks < 8; ++ks) {
            bf16x8 a[2];
            #pragma unroll
            for (int bn = 0; bn < 2; ++bn) {
                const size_t rr = (size_t)(row0 + bn * 16 + l16) * NHID;
                const float* s = (ks < 4)
                    ? (hidden + rr + ks * 32 + lq * 8)
                    : (x      + rr + (ks - 4) * 32 + lq * 8);
                f32x4 f0 = *(const f32x4*)(s);
                f32x4 f1 = *(const f32x4*)(s + 4);
                a[bn][0] = (bf16_t)f0.x; a[bn][1] = (bf16_t)f0.y;
                a[bn][2] = (bf16_t)f0.z; a[bn][3] = (bf16_t)f0.w;
                a[bn][4] = (bf16_t)f1.x; a[bn][5] = (bf16_t)f1.y;
                a[bn][6] = (bf16_t)f1.z; a[bn][7] = (bf16_t)f1.w;
            }
            #pragma unroll
            for (int pm = 0; pm < 4; ++pm) {
                acc[pm][0] = __builtin_amdgcn_mfma_f32_16x16x32_bf16(B1[pm * 8 + ks], a[0], acc[pm][0], 0, 0, 0);
                acc[pm][1] = __builtin_amdgcn_mfma_f32_16x16x32_bf16(B1[pm * 8 + ks], a[1], acc[pm][1], 0, 0, 0);
            }
        }

        // fused LSTM elementwise; immediate vectorized stores (no readers here)
        #pragma unroll
        for (int bn = 0; bn < 2; ++bn) {
            const size_t grow = (size_t)(row0 + bn * 16 + l16) * NHID + colb;
            const f32x4 fv = vsig(acc[0][bn] + bf4);
            const f32x4 iv = vsig(acc[1][bn] + bi4);
            const f32x4 cv = vtanh(acc[2][bn] + bc4);
            const f32x4 ov = vsig(acc[3][bn] + bo4);
            const f32x4 cn = fv * ctxA[bn] + iv * cv;
            const f32x4 hn = ov * vtanh(cn);
            *(f32x4*)(ctx_out + grow) = cn;
            *(f32x4*)(hid_out + grow) = hn;
        }
        ctxA[0] = ctxB[0];
        ctxA[1] = ctxB[1];
    }
}

// K2: out = hidden_new @ Wfc^T + bfc. Pure streaming GEMM, high occupancy.
__global__ __launch_bounds__(256, 4) void fc_out(
    const float* __restrict__ hid, const bf16_t* __restrict__ Wfcb,
    const float* __restrict__ bfc, float* __restrict__ out)
{
    const int tid  = threadIdx.x;
    const int lane = tid & 63;
    const int wq   = tid >> 6;     // 0..3 -> 32-col group
    const int l16  = lane & 15;
    const int lq   = lane >> 4;    // 0..3
    const int row0 = blockIdx.x * 32;

    // Wfc fragments for this wave's 32 out-cols (32 VGPR)
    bf16x8 Wr[2][4];
    #pragma unroll
    for (int pm = 0; pm < 2; ++pm)
        #pragma unroll
        for (int ks = 0; ks < 4; ++ks)
            Wr[pm][ks] = *(const bf16x8*)(Wfcb + (wq * 32 + pm * 16 + l16) * 128 + ks * 32 + lq * 8);
    const f32x4 b0 = *(const f32x4*)(bfc + wq * 32 +  0 + lq * 4);
    const f32x4 b1 = *(const f32x4*)(bfc + wq * 32 + 16 + lq * 4);

    f32x4 acc[2][2];
    #pragma unroll
    for (int pm = 0; pm < 2; ++pm) {
        acc[pm][0] = f32x4{0.f, 0.f, 0.f, 0.f};
        acc[pm][1] = f32x4{0.f, 0.f, 0.f, 0.f};
    }
    #pragma unroll
    for (int bn = 0; bn < 2; ++bn) {
        const float* hr = hid + (size_t)(row0 + bn * 16 + l16) * NHID;
        #pragma unroll
        for (int ks = 0; ks < 4; ++ks) {
            f32x4 f0 = *(const f32x4*)(hr + ks * 32 + lq * 8);
            f32x4 f1 = *(const f32x4*)(hr + ks * 32 + lq * 8 + 4);
            bf16x8 h;
            h[0] = (bf16_t)f0.x; h[1] = (bf16_t)f0.y;
            h[2] = (bf16_t)f0.z; h[3] = (bf16_t)f0.w;
            h[4] = (bf16_t)f1.x; h[5] = (bf16_t)f1.y;
            h[6] = (bf16_t)f1.z; h[7] = (bf16_t)f1.w;
            acc[0][bn] = __builtin_amdgcn_mfma_f32_16x16x32_bf16(Wr[0][ks], h, acc[0][bn], 0, 0, 0);
            acc[1][bn] = __builtin_amdgcn_mfma_f32_16x16x32_bf16(Wr[1][ks], h, acc[1][bn], 0, 0, 0);
        }
    }
    #pragma unroll
    for (int bn = 0; bn < 2; ++bn) {
        const size_t grow = (size_t)(row0 + bn * 16 + l16) * NHID + wq * 32;
        *(f32x4*)(out + grow + lq * 4)      = acc[0][bn] + b0;
        *(f32x4*)(out + grow + 16 + lq * 4) = acc[1][bn] + b1;
    }
}

extern "C" void kernel_launch(void* const* d_in, const int* in_sizes, int n_in,
                              void* d_out, int out_size, void* d_ws, size_t ws_size,
                              hipStream_t stream) {
    const float* x      = (const float*)d_in[0];
    const float* hidden = (const float*)d_in[1];
    const float* ctx    = (const float*)d_in[2];
    const float* Wf     = (const float*)d_in[3];
    const float* bfp    = (const float*)d_in[4];
    const float* Wi     = (const float*)d_in[5];
    const float* bip    = (const float*)d_in[6];
    const float* Wc     = (const float*)d_in[7];
    const float* bcp    = (const float*)d_in[8];
    const float* Wo     = (const float*)d_in[9];
    const float* bop    = (const float*)d_in[10];
    const float* Wfc    = (const float*)d_in[11];
    const float* bfc    = (const float*)d_in[12];

    bf16_t* W4p  = (bf16_t*)d_ws;                                   // 262144 B
    float*  b4p  = (float*)((char*)d_ws + 512 * 256 * 2);           // 2048 B
    bf16_t* Wfcb = (bf16_t*)((char*)d_ws + 512 * 256 * 2 + 2048);   // 32768 B

    prep_kernel<<<576, 256, 0, stream>>>(Wf, Wi, Wc, Wo, bfp, bip, bcp, bop, Wfc,
                                         W4p, b4p, Wfcb);

    float* outp    = (float*)d_out;
    float* hid_out = outp + (size_t)BATCH * NHID;
    float* ctx_out = outp + 2 * (size_t)BATCH * NHID;

    lstm_gates<<<NBLK, TPB, 0, stream>>>(x, hidden, ctx, W4p, b4p, hid_out, ctx_out);
    fc_out<<<NTILE, 256, 0, stream>>>(hid_out, Wfcb, bfc, outp);
}

// Round 11
// 125.979 us; speedup vs baseline: 1.8977x; 1.8977x over previous
//
#include <hip/hip_runtime.h>

#define BATCH   131072
#define NHID    128
#define KDIM    256     // n_in + n_hid
#define BM      32      // batch rows per tile
#define TPB     512     // 8 waves
#define NBLK    512     // 2 blocks per CU (16 waves/CU at <=128 VGPR)
#define NTILE   (BATCH / BM)     // 4096
#define TPBLK   (NTILE / NBLK)   // 8 tiles per block

typedef __bf16 bf16_t;
typedef __bf16 bf16x4 __attribute__((ext_vector_type(4)));
typedef __bf16 bf16x8 __attribute__((ext_vector_type(8)));
typedef float  f32x4  __attribute__((ext_vector_type(4)));

__device__ __forceinline__ float fsigmoid(float v) {
    return __builtin_amdgcn_rcpf(1.0f + __builtin_amdgcn_exp2f(v * -1.44269504f));
}
__device__ __forceinline__ float ftanh(float v) {
    return __builtin_fmaf(-2.0f,
        __builtin_amdgcn_rcpf(1.0f + __builtin_amdgcn_exp2f(v * 2.88539008f)), 1.0f);
}
__device__ __forceinline__ f32x4 vsig(f32x4 v) {
    f32x4 r;
    #pragma unroll
    for (int i = 0; i < 4; ++i) r[i] = fsigmoid(v[i]);
    return r;
}
__device__ __forceinline__ f32x4 vtanh(f32x4 v) {
    f32x4 r;
    #pragma unroll
    for (int i = 0; i < 4; ++i) r[i] = ftanh(v[i]);
    return r;
}

// Pack W4p[p][k] (bf16) with p = w*64 + t*16 + c  ->  gate t, output col j = w*16 + c.
__global__ void prep_kernel(const float* __restrict__ Wf, const float* __restrict__ Wi,
                            const float* __restrict__ Wc, const float* __restrict__ Wo,
                            const float* __restrict__ bfp, const float* __restrict__ bip,
                            const float* __restrict__ bcp, const float* __restrict__ bop,
                            const float* __restrict__ Wfc,
                            bf16_t* __restrict__ W4p, float* __restrict__ b4p,
                            bf16_t* __restrict__ Wfcb)
{
    int id = blockIdx.x * 256 + threadIdx.x;
    if (id < 512 * 256) {
        int p = id >> 8, k = id & 255;
        int w = p >> 6, t = (p >> 4) & 3, c = p & 15;
        int j = w * 16 + c;
        const float* W = (t == 0) ? Wf : (t == 1) ? Wi : (t == 2) ? Wc : Wo;
        W4p[id] = (bf16_t)W[j * 256 + k];
        if (k == 0) {
            const float* bs = (t == 0) ? bfp : (t == 1) ? bip : (t == 2) ? bcp : bop;
            b4p[p] = bs[j];
        }
    } else {
        int id2 = id - 512 * 256;
        if (id2 < 128 * 128) Wfcb[id2] = (bf16_t)Wfc[id2];
    }
}

__global__ __launch_bounds__(TPB, 2) void lstm_fused(
    const float* __restrict__ x, const float* __restrict__ hidden, const float* __restrict__ ctx,
    const bf16_t* __restrict__ W4p, const float* __restrict__ b4p,
    const bf16_t* __restrict__ Wfcb, const float* __restrict__ bfc,
    float* __restrict__ out, float* __restrict__ hid_out, float* __restrict__ ctx_out)
{
    // As[2]: bf16 [32][256] XOR-swizzled (2x16 KB) ; Hs[2]: bf16 [32][128] (2x8 KB)
    // 48 KB total -> 2 blocks co-resident per CU (96 <= 160 KB)
    __shared__ __align__(16) char lds[2 * 16384 + 2 * 8192];

    const int tid  = threadIdx.x;
    const int lane = tid & 63;
    const int wv   = tid >> 6;     // 0..7
    const int l16  = lane & 15;
    const int lq   = lane >> 4;    // 0..3
    const int tile0 = blockIdx.x * TPBLK;
    const int colb  = wv * 16 + lq * 4;     // this lane's 4 consecutive output cols
    const int swzA  = (l16 & 7) << 4;       // swizzle for LDS reads

    // stage-thread mapping
    const int r_s = tid >> 4;      // 0..31
    const int c_s = tid & 15;
    const int swzS = (r_s & 7) << 4;

    // ---- resident weights: B1 = this wave's 64 packed gate-rows (128 VGPR) ----
    bf16x8 B1[32];   // [pm*8 + ks]
    {
        const bf16_t* Bp = W4p + (wv * 64 + l16) * 256 + lq * 8;
        #pragma unroll
        for (int pm = 0; pm < 4; ++pm)
            #pragma unroll
            for (int ks = 0; ks < 8; ++ks)
                B1[pm * 8 + ks] = *(const bf16x8*)(Bp + pm * 16 * 256 + ks * 32);
    }
    bf16x8 b2r[4];
    {
        const bf16_t* B2 = Wfcb + (wv * 16 + l16) * 128 + lq * 8;
        #pragma unroll
        for (int ks = 0; ks < 4; ++ks) b2r[ks] = *(const bf16x8*)(B2 + ks * 32);
    }
    const f32x4 bf4  = *(const f32x4*)(b4p + wv * 64 +  0 + lq * 4);
    const f32x4 bi4  = *(const f32x4*)(b4p + wv * 64 + 16 + lq * 4);
    const f32x4 bc4  = *(const f32x4*)(b4p + wv * 64 + 32 + lq * 4);
    const f32x4 bo4  = *(const f32x4*)(b4p + wv * 64 + 48 + lq * 4);
    const f32x4 bfc4 = *(const f32x4*)(bfc + colb);

    f32x4 sv0, sv1, sv2, sv3;   // stage regs for tile t+1 (issued at iter top)
    f32x4 ctxA[2], ctxB[2];     // ctx for tile t / t+1

    // ---- prologue: stage tile0 -> As[0]; ctxA <- tile0 ----
    {
        const int grow = tile0 * BM + r_s;
        const float* hrow = hidden + (size_t)grow * NHID + c_s * 4;
        const float* xrow = x      + (size_t)grow * NHID + c_s * 4;
        f32x4 t0 = *(const f32x4*)(hrow);
        f32x4 t1 = *(const f32x4*)(hrow + 64);
        f32x4 t2 = *(const f32x4*)(xrow);
        f32x4 t3 = *(const f32x4*)(xrow + 64);
        char* A0 = lds;
        bf16x4 p0, p1, p2, p3;
        p0[0]=(bf16_t)t0.x; p0[1]=(bf16_t)t0.y; p0[2]=(bf16_t)t0.z; p0[3]=(bf16_t)t0.w;
        p1[0]=(bf16_t)t1.x; p1[1]=(bf16_t)t1.y; p1[2]=(bf16_t)t1.z; p1[3]=(bf16_t)t1.w;
        p2[0]=(bf16_t)t2.x; p2[1]=(bf16_t)t2.y; p2[2]=(bf16_t)t2.z; p2[3]=(bf16_t)t2.w;
        p3[0]=(bf16_t)t3.x; p3[1]=(bf16_t)t3.y; p3[2]=(bf16_t)t3.z; p3[3]=(bf16_t)t3.w;
        *(bf16x4*)(A0 + r_s * 512 + ((c_s * 8 +   0) ^ swzS)) = p0;
        *(bf16x4*)(A0 + r_s * 512 + ((c_s * 8 + 128) ^ swzS)) = p1;
        *(bf16x4*)(A0 + r_s * 512 + ((c_s * 8 + 256) ^ swzS)) = p2;
        *(bf16x4*)(A0 + r_s * 512 + ((c_s * 8 + 384) ^ swzS)) = p3;
    }
    {
        const float* cp = ctx + (size_t)(tile0 * BM) * NHID + colb;
        ctxA[0] = *(const f32x4*)(cp + (size_t)l16 * NHID);
        ctxA[1] = *(const f32x4*)(cp + (size_t)(16 + l16) * NHID);
    }
    __syncthreads();

    for (int t = 0; t < TPBLK; ++t) {
        const int P = t & 1;
        const int row0 = (tile0 + t) * BM;
        char* Asb = lds + P * 16384;
        char* Hsb = lds + 32768 + P * 8192;

        // ---- TOP: issue next tile's HBM loads (latency hides under GEMM1+epi) ----
        {
            const int tn = (t + 1 < TPBLK) ? t + 1 : TPBLK - 1;
            const int grow = (tile0 + tn) * BM + r_s;
            const float* hrow = hidden + (size_t)grow * NHID + c_s * 4;
            const float* xrow = x      + (size_t)grow * NHID + c_s * 4;
            sv0 = *(const f32x4*)(hrow);
            sv1 = *(const f32x4*)(hrow + 64);
            sv2 = *(const f32x4*)(xrow);
            sv3 = *(const f32x4*)(xrow + 64);
            const float* cp = ctx + (size_t)((tile0 + tn) * BM) * NHID + colb;
            ctxB[0] = *(const f32x4*)(cp + (size_t)l16 * NHID);
            ctxB[1] = *(const f32x4*)(cp + (size_t)(16 + l16) * NHID);
        }

        // ---- GEMM1 (transposed): gates^T = W4 . A^T ; acc[pm][bn] ----
        f32x4 acc[4][2];
        #pragma unroll
        for (int pm = 0; pm < 4; ++pm) {
            acc[pm][0] = f32x4{0.f, 0.f, 0.f, 0.f};
            acc[pm][1] = f32x4{0.f, 0.f, 0.f, 0.f};
        }
        #pragma unroll
        for (int ks = 0; ks < 8; ++ks) {
            const int kb = ks * 64 + lq * 16;
            bf16x8 a0 = *(const bf16x8*)(Asb + l16 * 512        + (kb ^ swzA));
            bf16x8 a1 = *(const bf16x8*)(Asb + (16 + l16) * 512 + (kb ^ swzA));
            #pragma unroll
            for (int pm = 0; pm < 4; ++pm) {
                acc[pm][0] = __builtin_amdgcn_mfma_f32_16x16x32_bf16(B1[pm * 8 + ks], a0, acc[pm][0], 0, 0, 0);
                acc[pm][1] = __builtin_amdgcn_mfma_f32_16x16x32_bf16(B1[pm * 8 + ks], a1, acc[pm][1], 0, 0, 0);
            }
        }

        // ---- fused LSTM elementwise, fully vectorized (4 cols per lane) ----
        #pragma unroll
        for (int bn = 0; bn < 2; ++bn) {
            const size_t grow = (size_t)(row0 + bn * 16 + l16) * NHID + colb;
            const f32x4 fv = vsig(acc[0][bn] + bf4);
            const f32x4 iv = vsig(acc[1][bn] + bi4);
            const f32x4 cv = vtanh(acc[2][bn] + bc4);
            const f32x4 ov = vsig(acc[3][bn] + bo4);
            const f32x4 cn = fv * ctxA[bn] + iv * cv;
            const f32x4 hn = ov * vtanh(cn);
            *(f32x4*)(ctx_out + grow) = cn;
            *(f32x4*)(hid_out + grow) = hn;
            bf16x4 hb;
            hb[0] = (bf16_t)hn.x; hb[1] = (bf16_t)hn.y;
            hb[2] = (bf16_t)hn.z; hb[3] = (bf16_t)hn.w;
            const int rh = bn * 16 + l16;
            *(bf16x4*)(Hsb + rh * 256 + ((wv * 32 + lq * 8) ^ ((rh & 7) << 4))) = hb;
        }
        ctxA[0] = ctxB[0];
        ctxA[1] = ctxB[1];

        // ---- stage write: tile t+1 (issued at top) -> As[P^1] ----
        {
            char* An = lds + (1 - P) * 16384;
            bf16x4 p0, p1, p2, p3;
            p0[0]=(bf16_t)sv0.x; p0[1]=(bf16_t)sv0.y; p0[2]=(bf16_t)sv0.z; p0[3]=(bf16_t)sv0.w;
            p1[0]=(bf16_t)sv1.x; p1[1]=(bf16_t)sv1.y; p1[2]=(bf16_t)sv1.z; p1[3]=(bf16_t)sv1.w;
            p2[0]=(bf16_t)sv2.x; p2[1]=(bf16_t)sv2.y; p2[2]=(bf16_t)sv2.z; p2[3]=(bf16_t)sv2.w;
            p3[0]=(bf16_t)sv3.x; p3[1]=(bf16_t)sv3.y; p3[2]=(bf16_t)sv3.z; p3[3]=(bf16_t)sv3.w;
            *(bf16x4*)(An + r_s * 512 + ((c_s * 8 +   0) ^ swzS)) = p0;
            *(bf16x4*)(An + r_s * 512 + ((c_s * 8 + 128) ^ swzS)) = p1;
            *(bf16x4*)(An + r_s * 512 + ((c_s * 8 + 256) ^ swzS)) = p2;
            *(bf16x4*)(An + r_s * 512 + ((c_s * 8 + 384) ^ swzS)) = p3;
        }

        __syncthreads();   // As[P^1] + Hs[P] visible (loads were issued ~2000cy ago)

        // ---- GEMM2 (transposed): out^T = Wfc . h^T ----
        f32x4 acc2[2];
        acc2[0] = f32x4{0.f, 0.f, 0.f, 0.f};
        acc2[1] = f32x4{0.f, 0.f, 0.f, 0.f};
        #pragma unroll
        for (int ks = 0; ks < 4; ++ks) {
            const int kb = ks * 64 + lq * 16;
            bf16x8 h0 = *(const bf16x8*)(Hsb + l16 * 256        + (kb ^ swzA));
            bf16x8 h1 = *(const bf16x8*)(Hsb + (16 + l16) * 256 + (kb ^ swzA));
            acc2[0] = __builtin_amdgcn_mfma_f32_16x16x32_bf16(b2r[ks], h0, acc2[0], 0, 0, 0);
            acc2[1] = __builtin_amdgcn_mfma_f32_16x16x32_bf16(b2r[ks], h1, acc2[1], 0, 0, 0);
        }
        #pragma unroll
        for (int bn = 0; bn < 2; ++bn) {
            const size_t grow = (size_t)(row0 + bn * 16 + l16) * NHID + colb;
            *(f32x4*)(out + grow) = acc2[bn] + bfc4;
        }
    }
}

extern "C" void kernel_launch(void* const* d_in, const int* in_sizes, int n_in,
                              void* d_out, int out_size, void* d_ws, size_t ws_size,
                              hipStream_t stream) {
    const float* x      = (const float*)d_in[0];
    const float* hidden = (const float*)d_in[1];
    const float* ctx    = (const float*)d_in[2];
    const float* Wf     = (const float*)d_in[3];
    const float* bfp    = (const float*)d_in[4];
    const float* Wi     = (const float*)d_in[5];
    const float* bip    = (const float*)d_in[6];
    const float* Wc     = (const float*)d_in[7];
    const float* bcp    = (const float*)d_in[8];
    const float* Wo     = (const float*)d_in[9];
    const float* bop    = (const float*)d_in[10];
    const float* Wfc    = (const float*)d_in[11];
    const float* bfc    = (const float*)d_in[12];

    bf16_t* W4p  = (bf16_t*)d_ws;                                   // 262144 B
    float*  b4p  = (float*)((char*)d_ws + 512 * 256 * 2);           // 2048 B
    bf16_t* Wfcb = (bf16_t*)((char*)d_ws + 512 * 256 * 2 + 2048);   // 32768 B

    prep_kernel<<<576, 256, 0, stream>>>(Wf, Wi, Wc, Wo, bfp, bip, bcp, bop, Wfc,
                                         W4p, b4p, Wfcb);

    float* outp = (float*)d_out;
    lstm_fused<<<NBLK, TPB, 0, stream>>>(
        x, hidden, ctx, W4p, b4p, Wfcb, bfc,
        outp,
        outp + (size_t)BATCH * NHID,
        outp + 2 * (size_t)BATCH * NHID);
}